// Round 15
// baseline (203.285 us; speedup 1.0000x reference)
//
#include <hip/hip_runtime.h>
#include <math.h>

#define BB 2
#define LL 2048
#define DIMM 1024
#define HH 16
#define DD 64
#define QKV_N 3072

typedef unsigned short u16;
typedef unsigned int u32;
typedef __attribute__((ext_vector_type(8))) short short8;   // 8 x bf16
typedef __attribute__((ext_vector_type(4))) float f32x4;

__device__ __forceinline__ float bf2f(u16 h) {
    unsigned u = ((unsigned)h) << 16;
    return __uint_as_float(u);
}
__device__ __forceinline__ u16 f2bf(float f) {
    unsigned u = __float_as_uint(f);
    u += 0x7fffu + ((u >> 16) & 1u);   // round-to-nearest-even
    return (u16)(u >> 16);
}
// pack two f32 -> (bf16(hi)<<16)|bf16(lo), round-half-up
__device__ __forceinline__ u32 pack_bf2(float lo, float hi) {
    u32 a = __float_as_uint(hi) + 0x8000u;
    u32 b = __float_as_uint(lo) + 0x8000u;
    return __builtin_amdgcn_perm(a, b, 0x07060302u);
}
// one-instruction f32 pair -> packed bf16 (T12 primitive; no builtin on gfx950)
__device__ __forceinline__ u32 cvtpk_bf2(float lo, float hi) {
    u32 r;
    asm("v_cvt_pk_bf16_f32 %0, %1, %2" : "=v"(r) : "v"(lo), "v"(hi));
    return r;
}
// async global->LDS, 16B per lane; LDS dst is wave-uniform base + lane*16
__device__ __forceinline__ void gload16(const u16* g, u16* l) {
    __builtin_amdgcn_global_load_lds(
        (const __attribute__((address_space(1))) void*)g,
        (__attribute__((address_space(3))) void*)l, 16, 0, 0);
}

// ---------------- fused conversions: convx | convt(frag) | convt(row) ---------
// One dispatch — identical per-block work, grid-partitioned.
// [0,2048): convx (x -> A-fragment-packed bf16).
// [2048,2816): convt fragmode=1 (w_qkv -> B-fragment-packed).
// [2816,3072): convt fragmode=0 (w_proj -> row-major [N][K] transpose).
__global__ __launch_bounds__(256) void conv_all(
    const float* __restrict__ X, u16* __restrict__ Af,
    const float* __restrict__ Wqkv, u16* __restrict__ Wqkvt,
    const float* __restrict__ Wproj, u16* __restrict__ Wprojt)
{
    const int tid = threadIdx.x;
    if (blockIdx.x < 2048) {
        // ---- convx: A-fragment pack ----
        const int g = blockIdx.x * 256 + tid;
        const int lane = g & 63;
        const int frag = g >> 6;              // 0..8191
        const int rt = frag >> 5;             // 0..255
        const int kts = (frag >> 1) & 15;     // 0..15
        const int ks2 = frag & 1;
        const int R = rt * 16 + (lane & 15);
        const int k = kts * 64 + ks2 * 32 + ((lane >> 4) & 3) * 8;
        float4 a = *(const float4*)&X[(size_t)R * DIMM + k];
        float4 b = *(const float4*)&X[(size_t)R * DIMM + k + 4];
        u16 t[8] = {f2bf(a.x), f2bf(a.y), f2bf(a.z), f2bf(a.w),
                    f2bf(b.x), f2bf(b.y), f2bf(b.z), f2bf(b.w)};
        *(uint4*)&Af[(size_t)frag * 512 + lane * 8] = *(uint4*)t;
        return;
    }

    __shared__ u16 s[64][72];
    const bool isfrag = (blockIdx.x < 2816);
    const int idx = isfrag ? (blockIdx.x - 2048) : (blockIdx.x - 2816);
    const int k0 = (idx & 15) * 64;
    const int n0 = (idx >> 4) * 64;
    const float* W = isfrag ? Wqkv : Wproj;
    u16* Wt = isfrag ? Wqkvt : Wprojt;
    const int K = 1024;
    const int N = isfrag ? QKV_N : DIMM;

#pragma unroll
    for (int t = 0; t < 16; ++t) {
        int flat = t * 256 + tid;
        int kk = flat >> 6, nn = flat & 63;
        s[nn][kk] = f2bf(W[(size_t)(k0 + kk) * N + n0 + nn]);
    }
    __syncthreads();
    if (isfrag) {
        const int kts = k0 >> 6;
        const int kdiv = K >> 6;
#pragma unroll
        for (int t2 = 0; t2 < 2; ++t2) {
            int i2 = t2 * 256 + tid;
            int fpart = i2 >> 6, lane_s = i2 & 63;   // 8 frags per 64x64 tile
            int ct = (n0 >> 4) + (fpart >> 1);
            int ks2 = fpart & 1;
            int nn = (fpart >> 1) * 16 + (lane_s & 15);
            int kk = ks2 * 32 + ((lane_s >> 4) & 3) * 8;
            *(uint4*)&Wt[((size_t)(ct * kdiv + kts) * 2 + ks2) * 512 + lane_s * 8]
                = *(const uint4*)&s[nn][kk];
        }
    } else {
#pragma unroll
        for (int t2 = 0; t2 < 2; ++t2) {
            int chunk = t2 * 256 + tid;
            int nn = chunk >> 3, kc = chunk & 7;
            *(uint4*)&Wt[(size_t)(n0 + nn) * K + k0 + kc * 8] = *(uint4*)&s[nn][kc * 8];
        }
    }
}

// ---------------- QKV GEMM: R8 split geometry, full-t ping-pong (R15) ---------
// R14 post-mortem: qkv_all latency-bound (387 TF, all pipes <16%) — the
// half-t ping-pong gave loads only ~80-160 cyc of cover vs ~200-400 cyc L2
// fragment latency, exposing residual every iteration. R15 extends the
// ping-pong to FULL iterations (two 16-frag banks, loads for t+2 issued
// right after bank-t's 32 MFMAs -> ~200+ cyc cover) — the same structure
// attn's K ping-pong proved the compiler will hold (R8: VGPR 96, stable).
// launch_bounds(256) = 512-reg cap: no spill cliff.
__global__ __launch_bounds__(256) void gemm_qkv_all(
    const u16* __restrict__ Af, const u16* __restrict__ Bf,
    u16* __restrict__ C, u16* __restrict__ kp, u16* __restrict__ vp,
    const float* __restrict__ pe,
    const float* __restrict__ qs, const float* __restrict__ ks)
{
    __shared__ u16 smem[17408];   // max(q:128*136, k/v:16384) u16

    const int region = blockIdx.x >> 8;    // 0=q, 1=k, 2=v
    const int bid = blockIdx.x & 255;

    const int tid = threadIdx.x;
    const int wave = tid >> 6, lane = tid & 63;
    const int mIdx = lane & 15, quad = lane >> 4;
    const int wr = wave >> 1, wc = wave & 1;
    // per-region: 256 blocks = 8 XCDs x 32; per-XCD chunk: 4m x 8n (L2-fit)
    const int xcd = bid & 7, lid = bid >> 3;
    const int m0 = (xcd * 4 + (lid >> 3)) * 128;
    const int nblk = lid & 7;
    const int n0 = region * 1024 + nblk * 128;
    const int N = QKV_N;

    // frag id = (rt*16 + t)*2 + ks2 (u16 offset frag*512); rt stride = 16384 u16
    const u16* abase = Af + ((size_t)((m0 >> 4) + 4 * wr)) * 16384 + lane * 8;
    const u16* bbase = Bf + ((size_t)((n0 >> 4) + 4 * wc)) * 16384 + lane * 8;

    f32x4 acc[4][4];
#pragma unroll
    for (int a = 0; a < 4; ++a)
#pragma unroll
        for (int b = 0; b < 4; ++b) acc[a][b] = (f32x4){0.f, 0.f, 0.f, 0.f};

    // two full-iteration banks: 16 frags each (ks2=0 pair + ks2=1 pair)
    short8 xA0[4], xB0[4], xA1[4], xB1[4];
    short8 yA0[4], yB0[4], yA1[4], yB1[4];

    auto loadt = [&](short8* A0, short8* B0, short8* A1, short8* B1, int t) {
        const size_t o0 = (size_t)t * 1024;
#pragma unroll
        for (int i = 0; i < 4; ++i) {
            A0[i] = *(const short8*)&abase[(size_t)i * 16384 + o0];
            B0[i] = *(const short8*)&bbase[(size_t)i * 16384 + o0];
        }
#pragma unroll
        for (int i = 0; i < 4; ++i) {
            A1[i] = *(const short8*)&abase[(size_t)i * 16384 + o0 + 512];
            B1[i] = *(const short8*)&bbase[(size_t)i * 16384 + o0 + 512];
        }
    };
    auto mfmat = [&](short8* A0, short8* B0, short8* A1, short8* B1) {
#pragma unroll
        for (int mt = 0; mt < 4; ++mt)
#pragma unroll
            for (int nt = 0; nt < 4; ++nt)
                acc[mt][nt] = __builtin_amdgcn_mfma_f32_16x16x32_bf16(
                    A0[mt], B0[nt], acc[mt][nt], 0, 0, 0);
#pragma unroll
        for (int mt = 0; mt < 4; ++mt)
#pragma unroll
            for (int nt = 0; nt < 4; ++nt)
                acc[mt][nt] = __builtin_amdgcn_mfma_f32_16x16x32_bf16(
                    A1[mt], B1[nt], acc[mt][nt], 0, 0, 0);
    };

    // prologue: banks hold t=0 and t=1
    loadt(xA0, xB0, xA1, xB1, 0);
    loadt(yA0, yB0, yA1, yB1, 1);
    __builtin_amdgcn_sched_barrier(0);

    for (int t2 = 0; t2 < 8; ++t2) {
        mfmat(xA0, xB0, xA1, xB1);                     // t = 2*t2
        __builtin_amdgcn_sched_barrier(0);
        if (t2 < 7) loadt(xA0, xB0, xA1, xB1, 2 * t2 + 2);
        __builtin_amdgcn_sched_barrier(0);
        mfmat(yA0, yB0, yA1, yB1);                     // t = 2*t2+1
        __builtin_amdgcn_sched_barrier(0);
        if (t2 < 7) loadt(yA0, yB0, yA1, yB1, 2 * t2 + 3);
        __builtin_amdgcn_sched_barrier(0);
    }

    if (region == 2) {
        // ---- v: assemble vpack tile (32 frags x 1KB) in LDS, store coalesced -
#pragma unroll
        for (int mt = 0; mt < 4; ++mt) {
            const int tl0 = 64 * wr + 16 * mt + 4 * quad;   // local key idx, %4==0
#pragma unroll
            for (int nt = 0; nt < 4; ++nt) {
                const int d = 16 * nt + mIdx;               // head-dim 0..63
                const int lblk = ((wc * 2 + (tl0 >> 6)) * 4 + (d >> 4)) * 2
                                 + ((tl0 >> 5) & 1);
                const int ln = (d & 15) + 16 * ((tl0 >> 3) & 3);
                uint2 pr;
                pr.x = pack_bf2(acc[mt][nt][0], acc[mt][nt][1]);
                pr.y = pack_bf2(acc[mt][nt][2], acc[mt][nt][3]);
                *(uint2*)&smem[lblk * 512 + ln * 8 + (tl0 & 7)] = pr;
            }
        }
        __syncthreads();
        {
            const int b = m0 >> 11;
            const int h0 = nblk * 2;
            const int ktb = (m0 & 2047) >> 6;
#pragma unroll
            for (int g2 = 0; g2 < 4; ++g2) {                // g2 = hh*2 + ktl
                const int bh = b * 16 + h0 + (g2 >> 1);
                const int kt = ktb + (g2 & 1);
                u16* dst = vp + ((size_t)(bh * 32 + kt) * 8) * 512;
                const u16* src = &smem[g2 * 8 * 512];
#pragma unroll
                for (int ps = 0; ps < 2; ++ps) {
                    const int off = (ps * 256 + tid) * 8;
                    *(uint4*)&dst[off] = *(const uint4*)&src[off];
                }
            }
        }
    } else {
        // ---- q/k: RMSNorm over head dim + RoPE; q prescaled log2e/8 ----------
        const float* scv = (region == 0) ? qs : ks;
        const float pre = (region == 0) ? 0.18033688011112042f : 1.0f;
        float scl[4];
#pragma unroll
        for (int nt = 0; nt < 4; ++nt) scl[nt] = scv[16 * nt + mIdx];

#pragma unroll
        for (int mt = 0; mt < 4; ++mt) {
#pragma unroll
            for (int r = 0; r < 4; ++r) {
                float s = 0.f;
#pragma unroll
                for (int nt = 0; nt < 4; ++nt) {
                    float a = acc[mt][nt][r];
                    s += a * a;
                }
                s += __shfl_xor(s, 1);
                s += __shfl_xor(s, 2);
                s += __shfl_xor(s, 4);
                s += __shfl_xor(s, 8);
                float rn = rsqrtf(s * (1.f / 64.f) + 1e-6f);
                const int tl = 64 * wr + 16 * mt + 4 * quad + r;   // local token
                const int R = m0 + tl;                              // = b*L + l
                size_t peo = (size_t)R * 128;
#pragma unroll
                for (int nt = 0; nt < 4; ++nt) {
                    float v = acc[mt][nt][r] * rn * scl[nt];
                    float pp = __shfl_xor(v, 1);
                    float2 pw = *(const float2*)&pe[peo + 2 * (16 * nt + mIdx)];
                    float e  = (mIdx & 1) ? pp : v;
                    float od = (mIdx & 1) ? v : pp;
                    u16 val = f2bf((pw.x * e + pw.y * od) * pre);
                    if (region == 0) {
                        smem[tl * 136 + 64 * wc + 16 * nt + mIdx] = val;
                    } else {
                        const int d = 16 * nt + mIdx;
                        const int lblk = ((wc * 2 + (tl >> 6)) * 4 + ((tl >> 4) & 3)) * 2
                                         + (d >> 5);
                        smem[lblk * 512 + ((tl & 15) + 16 * ((d >> 3) & 3)) * 8
                             + (d & 7)] = val;
                    }
                }
            }
        }
        __syncthreads();
        if (region == 0) {
            // coalesced q store: 8 x uint4 per thread
            const int row = tid >> 1, half = tid & 1;
            u16* dst = C + (size_t)(m0 + row) * QKV_N + n0 + half * 64;
            const u16* src = &smem[row * 136 + half * 64];
#pragma unroll
            for (int c = 0; c < 8; ++c)
                *(uint4*)&dst[c * 8] = *(const uint4*)&src[c * 8];
        } else {
            const int b = m0 >> 11;
            const int h0 = nblk * 2;
            const int ktb = (m0 & 2047) >> 6;
#pragma unroll
            for (int g2 = 0; g2 < 4; ++g2) {                // g2 = hh*2 + ktl
                const int bh = b * 16 + h0 + (g2 >> 1);
                const int kt = ktb + (g2 & 1);
                u16* dst = kp + ((size_t)(bh * 32 + kt) * 8) * 512;
                const u16* src = &smem[g2 * 8 * 512];
#pragma unroll
                for (int ps = 0; ps < 2; ++ps) {
                    const int off = (ps * 256 + tid) * 8;
                    *(uint4*)&dst[off] = *(const uint4*)&src[off];
                }
            }
        }
    }
}

// ---------------- proj GEMM: 2-phase double-buffered, 64x128 tile (R8) --------
__global__ __launch_bounds__(256) void gemm_proj(
    const u16* __restrict__ A, const u16* __restrict__ Bt,
    const float* __restrict__ bias, float* __restrict__ C)
{
    __shared__ u16 smem[2 * 12288];   // [dbuf][sA(4K u16) | sB(8K u16)] = 48KB

    const int tid = threadIdx.x;
    const int wave = tid >> 6, lane = tid & 63;
    const int mIdx = lane & 15, quad = lane >> 4;
    const int wr = wave >> 1, wc = wave & 1;   // 2x2 waves of 32x64
    const int xcd = blockIdx.x & 7, lid = blockIdx.x >> 3;
    const int m0 = (xcd * 8 + (lid >> 3)) * 64;
    const int n0 = (lid & 7) * 128;
    const int N = DIMM, K = DIMM;
    const int lr = lane >> 3, lc = lane & 7;

    f32x4 acc[2][4];
#pragma unroll
    for (int a = 0; a < 2; ++a)
#pragma unroll
        for (int b = 0; b < 4; ++b) acc[a][b] = (f32x4){0.f, 0.f, 0.f, 0.f};

    auto stage = [&](int buf, int k0) {
        u16* sA = smem + buf * 12288;
        u16* sB = sA + 4096;
#pragma unroll
        for (int j = 0; j < 2; ++j) {       // A: 64 rows
            int r0 = 16 * wave + 8 * j + lr;
            gload16(&A[(size_t)(m0 + r0) * K + k0 + 8 * (lc ^ lr)],
                    &sA[(16 * wave + 8 * j) * 64]);
        }
#pragma unroll
        for (int j = 0; j < 4; ++j) {       // B: 128 rows
            int r0 = 32 * wave + 8 * j + lr;
            gload16(&Bt[(size_t)(n0 + r0) * K + k0 + 8 * (lc ^ lr)],
                    &sB[(32 * wave + 8 * j) * 64]);
        }
    };

    stage(0, 0);
    __syncthreads();
    int cur = 0;
    for (int t = 0; t < 16; ++t) {
        if (t + 1 < 16) stage(cur ^ 1, (t + 1) * 64);
        const u16* sA = smem + cur * 12288;
        const u16* sB = sA + 4096;
#pragma unroll
        for (int ks2 = 0; ks2 < 2; ++ks2) {
            short8 af[2], bfr[4];
#pragma unroll
            for (int mt = 0; mt < 2; ++mt) {
                int Ra = 32 * wr + 16 * mt + mIdx;
                af[mt] = *(const short8*)&sA[Ra * 64 + 8 * ((ks2 * 4 + quad) ^ (Ra & 7))];
            }
#pragma unroll
            for (int nt = 0; nt < 4; ++nt) {
                int Rb = 64 * wc + 16 * nt + mIdx;
                bfr[nt] = *(const short8*)&sB[Rb * 64 + 8 * ((ks2 * 4 + quad) ^ (Rb & 7))];
            }
#pragma unroll
            for (int mt = 0; mt < 2; ++mt)
#pragma unroll
                for (int nt = 0; nt < 4; ++nt)
                    acc[mt][nt] = __builtin_amdgcn_mfma_f32_16x16x32_bf16(
                        af[mt], bfr[nt], acc[mt][nt], 0, 0, 0);
        }
        __syncthreads();
        cur ^= 1;
    }

#pragma unroll
    for (int mt = 0; mt < 2; ++mt)
#pragma unroll
        for (int r = 0; r < 4; ++r) {
            int row = m0 + 32 * wr + 16 * mt + quad * 4 + r;
#pragma unroll
            for (int nt = 0; nt < 4; ++nt) {
                int col = n0 + 64 * wc + 16 * nt + mIdx;
                C[(size_t)row * N + col] = acc[mt][nt][r] + bias[col];
            }
        }
}

// ---------------- flash attention: fragment-direct, barrier-free (R8) ---------
// 128-row 2-group structure (66us, VGPR 96, 2 blocks/CU): proven local optimum.
__global__ __launch_bounds__(256, 2) void attn_mfma(
    const u16* __restrict__ qkv, const u16* __restrict__ kp,
    const u16* __restrict__ vp, u16* __restrict__ o)
{
    __shared__ u16 sP[128 * 64];

    const int tid = threadIdx.x;
    const int wave = tid >> 6;     // 0..3
    const int lane = tid & 63;
    const int mIdx = lane & 15;
    const int quad = lane >> 4;
    const int m7 = mIdx & 7;

    // XCD-chunked swizzle (512 blocks, 8 XCDs, 64 logical blocks per XCD)
    const int bid = ((blockIdx.x & 7) << 6) | (blockIdx.x >> 3);
    const int bh = bid >> 4;          // 16 q-tiles of 128 rows per (b,h)
    const int qt = bid & 15;
    const int b = bh >> 4, h = bh & 15;
    const int q0 = qt * 128;

    // fragment bases: tile kt at +kt*4096 u16; fragment f=nb*2+c at +f*512
    const u16* kbase = kp + (size_t)bh * 32 * 4096 + lane * 8;
    const u16* vbase = vp + (size_t)bh * 32 * 4096 + lane * 8;

    // Q fragments: 2 groups of 16 rows per wave
    short8 aq[2][2];
#pragma unroll
    for (int g = 0; g < 2; ++g) {
        const u16* qrow = qkv + (size_t)b * LL * QKV_N + h * 64
                          + (size_t)(q0 + 32 * wave + 16 * g + mIdx) * QKV_N;
        aq[g][0] = *(const short8*)&qrow[quad * 8];
        aq[g][1] = *(const short8*)&qrow[32 + quad * 8];
    }

    const short8 bones = {(short)0x3F80, (short)0x3F80, (short)0x3F80, (short)0x3F80,
                          (short)0x3F80, (short)0x3F80, (short)0x3F80, (short)0x3F80};

    f32x4 Oacc[2][4];
    f32x4 lac[2];
#pragma unroll
    for (int g = 0; g < 2; ++g) {
        lac[g] = (f32x4){0.f, 0.f, 0.f, 0.f};
#pragma unroll
        for (int nb = 0; nb < 4; ++nb) Oacc[g][nb] = (f32x4){0.f, 0.f, 0.f, 0.f};
    }

    // P swizzle offsets (proven pattern)
    const int o0 = 8 * (quad ^ m7);
    const int o1 = 8 * ((quad + 4) ^ m7);
    u16* sPr0 = &sP[(32 * wave + mIdx) * 64];
    u16* sPr1 = &sP[(32 * wave + 16 + mIdx) * 64];

    short8 kfA[8], kfB[8], vf[8];

    // prologue: K fragments of tile 0
#pragma unroll
    for (int f = 0; f < 8; ++f) kfA[f] = *(const short8*)&kbase[f * 512];

    auto body = [&](short8* KC, short8* KN, int kt) {
        const size_t tb = (size_t)kt * 4096;
        // V fragments for THIS tile (consumed after S^T phase)
#pragma unroll
        for (int f = 0; f < 8; ++f) vf[f] = *(const short8*)&vbase[tb + f * 512];
        // K fragments for NEXT tile (consumed next body)
        if (kt < 31) {
#pragma unroll
            for (int f = 0; f < 8; ++f) KN[f] = *(const short8*)&kbase[tb + 4096 + f * 512];
        }
        __builtin_amdgcn_sched_barrier(0);

        // ---- S^T strips: D[key][q] = mfma(A=K-frag, B=Q-frag) ----
#pragma unroll
        for (int nb = 0; nb < 4; ++nb) {
            const int pofs = (16 * nb + 4 * quad) ^ (8 * m7);
#pragma unroll
            for (int g = 0; g < 2; ++g) {
                f32x4 st = (f32x4){0.f, 0.f, 0.f, 0.f};
                st = __builtin_amdgcn_mfma_f32_16x16x32_bf16(KC[nb * 2 + 0], aq[g][0], st, 0, 0, 0);
                st = __builtin_amdgcn_mfma_f32_16x16x32_bf16(KC[nb * 2 + 1], aq[g][1], st, 0, 0, 0);
                float p0 = exp2f(st[0]), p1 = exp2f(st[1]);
                float p2 = exp2f(st[2]), p3 = exp2f(st[3]);
                uint2 wp;
                wp.x = cvtpk_bf2(p0, p1);
                wp.y = cvtpk_bf2(p2, p3);
                *(uint2*)&((g == 0 ? sPr0 : sPr1)[pofs]) = wp;
            }
        }
        // sP rows written and read by the same wave -> no barrier.
        short8 pa00 = *(const short8*)&sPr0[o0];
        short8 pa01 = *(const short8*)&sPr0[o1];
        short8 pa10 = *(const short8*)&sPr1[o0];
        short8 pa11 = *(const short8*)&sPr1[o1];

        // l accumulation via MFMA with all-ones B (no VALU adds, no shuffles)
        lac[0] = __builtin_amdgcn_mfma_f32_16x16x32_bf16(pa00, bones, lac[0], 0, 0, 0);
        lac[0] = __builtin_amdgcn_mfma_f32_16x16x32_bf16(pa01, bones, lac[0], 0, 0, 0);
        lac[1] = __builtin_amdgcn_mfma_f32_16x16x32_bf16(pa10, bones, lac[1], 0, 0, 0);
        lac[1] = __builtin_amdgcn_mfma_f32_16x16x32_bf16(pa11, bones, lac[1], 0, 0, 0);

        // ---- O += P @ V ----
        __builtin_amdgcn_s_setprio(1);
#pragma unroll
        for (int nb = 0; nb < 4; ++nb) {
            Oacc[0][nb] = __builtin_amdgcn_mfma_f32_16x16x32_bf16(pa00, vf[nb * 2 + 0], Oacc[0][nb], 0, 0, 0);
            Oacc[0][nb] = __builtin_amdgcn_mfma_f32_16x16x32_bf16(pa01, vf[nb * 2 + 1], Oacc[0][nb], 0, 0, 0);
            Oacc[1][nb] = __builtin_amdgcn_mfma_f32_16x16x32_bf16(pa10, vf[nb * 2 + 0], Oacc[1][nb], 0, 0, 0);
            Oacc[1][nb] = __builtin_amdgcn_mfma_f32_16x16x32_bf16(pa11, vf[nb * 2 + 1], Oacc[1][nb], 0, 0, 0);
        }
        __builtin_amdgcn_s_setprio(0);
    };

    for (int kt2 = 0; kt2 < 16; ++kt2) {
        body(kfA, kfB, 2 * kt2);
        body(kfB, kfA, 2 * kt2 + 1);
    }

    // epilogue: l for q-row quad*4+r (within group g) sits in lac[g][r] of
    // EVERY lane (all-ones B makes all columns equal) — no shuffles needed.
#pragma unroll
    for (int g = 0; g < 2; ++g)
#pragma unroll
        for (int r = 0; r < 4; ++r) {
            float linv = 1.f / lac[g][r];
            const int rowg = b * LL + q0 + 32 * wave + 16 * g + quad * 4 + r;
#pragma unroll
            for (int nb = 0; nb < 4; ++nb) {
                o[(size_t)rowg * DIMM + h * 64 + 16 * nb + mIdx] =
                    f2bf(Oacc[g][nb][r] * linv);
            }
        }
}

extern "C" void kernel_launch(void* const* d_in, const int* in_sizes, int n_in,
                              void* d_out, int out_size, void* d_ws, size_t ws_size,
                              hipStream_t stream) {
    const float* x       = (const float*)d_in[0];
    const float* pe      = (const float*)d_in[1];
    const float* w_qkv   = (const float*)d_in[2];
    const float* q_scale = (const float*)d_in[3];
    const float* k_scale = (const float*)d_in[4];
    const float* w_proj  = (const float*)d_in[5];
    const float* b_proj  = (const float*)d_in[6];
    float* out = (float*)d_out;

    char* ws = (char*)d_ws;
    u16* qkv    = (u16*)ws;  ws += (size_t)4096 * 3072 * 2;
    u16* o      = (u16*)ws;  ws += (size_t)4096 * 1024 * 2;
    u16* xb     = (u16*)ws;  ws += (size_t)4096 * 1024 * 2;   // A-fragment-packed
    u16* wqkvt  = (u16*)ws;  ws += (size_t)3072 * 1024 * 2;   // B-fragment-packed
    u16* wprojt = (u16*)ws;  ws += (size_t)1024 * 1024 * 2;   // row-major [N][K]
    u16* kpack  = (u16*)ws;  ws += (size_t)32 * 32 * 4096 * 2;   // 8.4 MB
    u16* vpack  = (u16*)ws;  ws += (size_t)32 * 32 * 4096 * 2;   // 8.4 MB

    // 0. all conversions in ONE dispatch
    conv_all<<<3072, 256, 0, stream>>>(x, xb, w_qkv, wqkvt, w_proj, wprojt);

    // 1. QKV projection: single dispatch, full-t ping-pong (R15)
    gemm_qkv_all<<<768, 256, 0, stream>>>(
        xb, wqkvt, qkv, kpack, vpack, pe, q_scale, k_scale);

    // 2. attention (R8: 128-row tiles, K ping-pong, VGPR 96)
    attn_mfma<<<BB * HH * (LL / 128), 256, 0, stream>>>(qkv, kpack, vpack, o);

    // 3. output projection + bias (f32 out)
    gemm_proj<<<512, 256, 0, stream>>>(o, wprojt, b_proj, out);
}

// Round 16
// 197.110 us; speedup vs baseline: 1.0313x; 1.0313x over previous
//
#include <hip/hip_runtime.h>
#include <math.h>

#define BB 2
#define LL 2048
#define DIMM 1024
#define HH 16
#define DD 64
#define QKV_N 3072

typedef unsigned short u16;
typedef unsigned int u32;
typedef __attribute__((ext_vector_type(8))) short short8;   // 8 x bf16
typedef __attribute__((ext_vector_type(4))) float f32x4;

__device__ __forceinline__ float bf2f(u16 h) {
    unsigned u = ((unsigned)h) << 16;
    return __uint_as_float(u);
}
__device__ __forceinline__ u16 f2bf(float f) {
    unsigned u = __float_as_uint(f);
    u += 0x7fffu + ((u >> 16) & 1u);   // round-to-nearest-even
    return (u16)(u >> 16);
}
// pack two f32 -> (bf16(hi)<<16)|bf16(lo), round-half-up
__device__ __forceinline__ u32 pack_bf2(float lo, float hi) {
    u32 a = __float_as_uint(hi) + 0x8000u;
    u32 b = __float_as_uint(lo) + 0x8000u;
    return __builtin_amdgcn_perm(a, b, 0x07060302u);
}
// one-instruction f32 pair -> packed bf16 (T12 primitive; no builtin on gfx950)
__device__ __forceinline__ u32 cvtpk_bf2(float lo, float hi) {
    u32 r;
    asm("v_cvt_pk_bf16_f32 %0, %1, %2" : "=v"(r) : "v"(lo), "v"(hi));
    return r;
}
// async global->LDS, 16B per lane; LDS dst is wave-uniform base + lane*16
__device__ __forceinline__ void gload16(const u16* g, u16* l) {
    __builtin_amdgcn_global_load_lds(
        (const __attribute__((address_space(1))) void*)g,
        (__attribute__((address_space(3))) void*)l, 16, 0, 0);
}

// ---------------- fused conversions: convx | convt(frag) | convt(row) ---------
__global__ __launch_bounds__(256) void conv_all(
    const float* __restrict__ X, u16* __restrict__ Af,
    const float* __restrict__ Wqkv, u16* __restrict__ Wqkvt,
    const float* __restrict__ Wproj, u16* __restrict__ Wprojt)
{
    const int tid = threadIdx.x;
    if (blockIdx.x < 2048) {
        // ---- convx: A-fragment pack ----
        const int g = blockIdx.x * 256 + tid;
        const int lane = g & 63;
        const int frag = g >> 6;              // 0..8191
        const int rt = frag >> 5;             // 0..255
        const int kts = (frag >> 1) & 15;     // 0..15
        const int ks2 = frag & 1;
        const int R = rt * 16 + (lane & 15);
        const int k = kts * 64 + ks2 * 32 + ((lane >> 4) & 3) * 8;
        float4 a = *(const float4*)&X[(size_t)R * DIMM + k];
        float4 b = *(const float4*)&X[(size_t)R * DIMM + k + 4];
        u16 t[8] = {f2bf(a.x), f2bf(a.y), f2bf(a.z), f2bf(a.w),
                    f2bf(b.x), f2bf(b.y), f2bf(b.z), f2bf(b.w)};
        *(uint4*)&Af[(size_t)frag * 512 + lane * 8] = *(uint4*)t;
        return;
    }

    __shared__ u16 s[64][72];
    const bool isfrag = (blockIdx.x < 2816);
    const int idx = isfrag ? (blockIdx.x - 2048) : (blockIdx.x - 2816);
    const int k0 = (idx & 15) * 64;
    const int n0 = (idx >> 4) * 64;
    const float* W = isfrag ? Wqkv : Wproj;
    u16* Wt = isfrag ? Wqkvt : Wprojt;
    const int K = 1024;
    const int N = isfrag ? QKV_N : DIMM;

#pragma unroll
    for (int t = 0; t < 16; ++t) {
        int flat = t * 256 + tid;
        int kk = flat >> 6, nn = flat & 63;
        s[nn][kk] = f2bf(W[(size_t)(k0 + kk) * N + n0 + nn]);
    }
    __syncthreads();
    if (isfrag) {
        const int kts = k0 >> 6;
        const int kdiv = K >> 6;
#pragma unroll
        for (int t2 = 0; t2 < 2; ++t2) {
            int i2 = t2 * 256 + tid;
            int fpart = i2 >> 6, lane_s = i2 & 63;   // 8 frags per 64x64 tile
            int ct = (n0 >> 4) + (fpart >> 1);
            int ks2 = fpart & 1;
            int nn = (fpart >> 1) * 16 + (lane_s & 15);
            int kk = ks2 * 32 + ((lane_s >> 4) & 3) * 8;
            *(uint4*)&Wt[((size_t)(ct * kdiv + kts) * 2 + ks2) * 512 + lane_s * 8]
                = *(const uint4*)&s[nn][kk];
        }
    } else {
#pragma unroll
        for (int t2 = 0; t2 < 2; ++t2) {
            int chunk = t2 * 256 + tid;
            int nn = chunk >> 3, kc = chunk & 7;
            *(uint4*)&Wt[(size_t)(n0 + nn) * K + k0 + kc * 8] = *(uint4*)&s[nn][kc * 8];
        }
    }
}

// ---------------- QKV GEMM: 128x64 tiles, 2x TLP (R16) ------------------------
// R15 post-mortem: 4th failure of deeper register pipelining (compiler
// collapses >~100-VGPR pipelined state; VGPR 128, dur 74us). Per-wave ILP
// is exhausted -> the remaining lever for this latency-bound loop is TLP,
// and R14 was grid-limited (768 blocks = 3/CU, occupancy 17.7%).
// R16: 128m x 64n tiles -> 1536 blocks = 6 blocks/CU, 24 waves/CU (2x).
// Per wave: acc[2][4], half-t ping-pong (R14's proven structure), ~70 VGPR.
// Each tile = exactly one head for q/k/v -> simpler epilogues.
// XCD chunk per region: 4m x 16n -> A 1MB + B 2MB (L2-fit, as R14).
__global__ __launch_bounds__(256) void gemm_qkv_all(
    const u16* __restrict__ Af, const u16* __restrict__ Bf,
    u16* __restrict__ C, u16* __restrict__ kp, u16* __restrict__ vp,
    const float* __restrict__ pe,
    const float* __restrict__ qs, const float* __restrict__ ks)
{
    __shared__ u16 smem[9216];   // q: [128][72]=9216 u16; k/v: 16 frags = 8192 u16

    const int region = blockIdx.x >> 9;    // 0=q, 1=k, 2=v  (512 blocks each)
    const int bid = blockIdx.x & 511;

    const int tid = threadIdx.x;
    const int wave = tid >> 6, lane = tid & 63;
    const int mIdx = lane & 15, quad = lane >> 4;
    // per-region: 512 blocks = 8 XCDs x 64; per-XCD chunk: 4m x 16n
    const int xcd = bid & 7, lid = bid >> 3;
    const int m0 = (xcd * 4 + (lid >> 4)) * 128;
    const int nblk = lid & 15;             // head index within region
    const int n0 = region * 1024 + nblk * 64;

    // frag id = (rt*16 + t)*2 + ks2 (u16 offset frag*512); rt stride = 16384 u16
    const u16* abase = Af + ((size_t)((m0 >> 4) + 2 * wave)) * 16384 + lane * 8;
    const u16* bbase = Bf + ((size_t)(n0 >> 4)) * 16384 + lane * 8;

    f32x4 acc[2][4];
#pragma unroll
    for (int a = 0; a < 2; ++a)
#pragma unroll
        for (int b = 0; b < 4; ++b) acc[a][b] = (f32x4){0.f, 0.f, 0.f, 0.f};

    short8 aA[2], bA[4], aB[2], bB[4];
#pragma unroll
    for (int i = 0; i < 2; ++i) aA[i] = *(const short8*)&abase[(size_t)i * 16384];
#pragma unroll
    for (int i = 0; i < 4; ++i) bA[i] = *(const short8*)&bbase[(size_t)i * 16384];

    for (int t = 0; t < 16; ++t) {
        const size_t o1 = (size_t)t * 1024 + 512;          // (t, ks2=1)
#pragma unroll
        for (int i = 0; i < 2; ++i) aB[i] = *(const short8*)&abase[(size_t)i * 16384 + o1];
#pragma unroll
        for (int i = 0; i < 4; ++i) bB[i] = *(const short8*)&bbase[(size_t)i * 16384 + o1];
        __builtin_amdgcn_sched_barrier(0);
#pragma unroll
        for (int mt = 0; mt < 2; ++mt)
#pragma unroll
            for (int nt = 0; nt < 4; ++nt)
                acc[mt][nt] = __builtin_amdgcn_mfma_f32_16x16x32_bf16(
                    aA[mt], bA[nt], acc[mt][nt], 0, 0, 0);
        __builtin_amdgcn_sched_barrier(0);
        if (t + 1 < 16) {
            const size_t o0 = (size_t)(t + 1) * 1024;      // (t+1, ks2=0)
#pragma unroll
            for (int i = 0; i < 2; ++i) aA[i] = *(const short8*)&abase[(size_t)i * 16384 + o0];
#pragma unroll
            for (int i = 0; i < 4; ++i) bA[i] = *(const short8*)&bbase[(size_t)i * 16384 + o0];
        }
        __builtin_amdgcn_sched_barrier(0);
#pragma unroll
        for (int mt = 0; mt < 2; ++mt)
#pragma unroll
            for (int nt = 0; nt < 4; ++nt)
                acc[mt][nt] = __builtin_amdgcn_mfma_f32_16x16x32_bf16(
                    aB[mt], bB[nt], acc[mt][nt], 0, 0, 0);
        __builtin_amdgcn_sched_barrier(0);
    }

    const int b = m0 >> 11;                // batch
    const int ktb = (m0 & 2047) >> 6;      // first 64-token tile index
    const int bh = b * 16 + nblk;          // (batch, head)

    if (region == 2) {
        // ---- v: assemble 16 frags (2 kt x 4 dq x 2 th) in LDS, store ----
#pragma unroll
        for (int mt = 0; mt < 2; ++mt) {
            const int tl0 = 32 * wave + 16 * mt + 4 * quad;   // local token, %4==0
#pragma unroll
            for (int nt = 0; nt < 4; ++nt) {
                const int d = 16 * nt + mIdx;                 // head-dim 0..63
                const int lblk = ((tl0 >> 6) * 4 + (d >> 4)) * 2 + ((tl0 >> 5) & 1);
                const int ln = (d & 15) + 16 * ((tl0 >> 3) & 3);
                uint2 pr;
                pr.x = pack_bf2(acc[mt][nt][0], acc[mt][nt][1]);
                pr.y = pack_bf2(acc[mt][nt][2], acc[mt][nt][3]);
                *(uint2*)&smem[lblk * 512 + ln * 8 + (tl0 & 7)] = pr;
            }
        }
        __syncthreads();
#pragma unroll
        for (int ktl = 0; ktl < 2; ++ktl) {
            u16* dst = vp + ((size_t)(bh * 32 + ktb + ktl) * 8) * 512;
            const u16* src = &smem[ktl * 8 * 512];
#pragma unroll
            for (int ps = 0; ps < 2; ++ps) {
                const int off = (ps * 256 + tid) * 8;
                *(uint4*)&dst[off] = *(const uint4*)&src[off];
            }
        }
    } else {
        // ---- q/k: RMSNorm over head dim + RoPE; q prescaled log2e/8 ----------
        const float* scv = (region == 0) ? qs : ks;
        const float pre = (region == 0) ? 0.18033688011112042f : 1.0f;
        float scl[4];
#pragma unroll
        for (int nt = 0; nt < 4; ++nt) scl[nt] = scv[16 * nt + mIdx];

#pragma unroll
        for (int mt = 0; mt < 2; ++mt) {
#pragma unroll
            for (int r = 0; r < 4; ++r) {
                float s = 0.f;
#pragma unroll
                for (int nt = 0; nt < 4; ++nt) {
                    float a = acc[mt][nt][r];
                    s += a * a;
                }
                s += __shfl_xor(s, 1);
                s += __shfl_xor(s, 2);
                s += __shfl_xor(s, 4);
                s += __shfl_xor(s, 8);
                float rn = rsqrtf(s * (1.f / 64.f) + 1e-6f);
                const int tl = 32 * wave + 16 * mt + 4 * quad + r;   // local token
                const int R = m0 + tl;                               // = b*L + l
                size_t peo = (size_t)R * 128;
#pragma unroll
                for (int nt = 0; nt < 4; ++nt) {
                    const int d = 16 * nt + mIdx;
                    float v = acc[mt][nt][r] * rn * scl[nt];
                    float pp = __shfl_xor(v, 1);
                    float2 pw = *(const float2*)&pe[peo + 2 * d];
                    float e  = (mIdx & 1) ? pp : v;
                    float od = (mIdx & 1) ? v : pp;
                    u16 val = f2bf((pw.x * e + pw.y * od) * pre);
                    if (region == 0) {
                        smem[tl * 72 + d] = val;
                    } else {
                        const int lblk = ((tl >> 6) * 4 + ((tl >> 4) & 3)) * 2 + (d >> 5);
                        smem[lblk * 512 + ((tl & 15) + 16 * ((d >> 3) & 3)) * 8 + (d & 7)] = val;
                    }
                }
            }
        }
        __syncthreads();
        if (region == 0) {
            // coalesced q store: 128 rows x 64 u16; 4 x uint4 per thread
            const int row = tid >> 1, half = tid & 1;
            u16* dst = C + (size_t)(m0 + row) * QKV_N + n0 + half * 32;
            const u16* src = &smem[row * 72 + half * 32];
#pragma unroll
            for (int c = 0; c < 4; ++c)
                *(uint4*)&dst[c * 8] = *(const uint4*)&src[c * 8];
        } else {
#pragma unroll
            for (int ktl = 0; ktl < 2; ++ktl) {
                u16* dst = kp + ((size_t)(bh * 32 + ktb + ktl) * 8) * 512;
                const u16* src = &smem[ktl * 8 * 512];
#pragma unroll
                for (int ps = 0; ps < 2; ++ps) {
                    const int off = (ps * 256 + tid) * 8;
                    *(uint4*)&dst[off] = *(const uint4*)&src[off];
                }
            }
        }
    }
}

// ---------------- proj GEMM: 2-phase double-buffered, 64x128 tile (R8) --------
__global__ __launch_bounds__(256) void gemm_proj(
    const u16* __restrict__ A, const u16* __restrict__ Bt,
    const float* __restrict__ bias, float* __restrict__ C)
{
    __shared__ u16 smem[2 * 12288];   // [dbuf][sA(4K u16) | sB(8K u16)] = 48KB

    const int tid = threadIdx.x;
    const int wave = tid >> 6, lane = tid & 63;
    const int mIdx = lane & 15, quad = lane >> 4;
    const int wr = wave >> 1, wc = wave & 1;   // 2x2 waves of 32x64
    const int xcd = blockIdx.x & 7, lid = blockIdx.x >> 3;
    const int m0 = (xcd * 8 + (lid >> 3)) * 64;
    const int n0 = (lid & 7) * 128;
    const int N = DIMM, K = DIMM;
    const int lr = lane >> 3, lc = lane & 7;

    f32x4 acc[2][4];
#pragma unroll
    for (int a = 0; a < 2; ++a)
#pragma unroll
        for (int b = 0; b < 4; ++b) acc[a][b] = (f32x4){0.f, 0.f, 0.f, 0.f};

    auto stage = [&](int buf, int k0) {
        u16* sA = smem + buf * 12288;
        u16* sB = sA + 4096;
#pragma unroll
        for (int j = 0; j < 2; ++j) {       // A: 64 rows
            int r0 = 16 * wave + 8 * j + lr;
            gload16(&A[(size_t)(m0 + r0) * K + k0 + 8 * (lc ^ lr)],
                    &sA[(16 * wave + 8 * j) * 64]);
        }
#pragma unroll
        for (int j = 0; j < 4; ++j) {       // B: 128 rows
            int r0 = 32 * wave + 8 * j + lr;
            gload16(&Bt[(size_t)(n0 + r0) * K + k0 + 8 * (lc ^ lr)],
                    &sB[(32 * wave + 8 * j) * 64]);
        }
    };

    stage(0, 0);
    __syncthreads();
    int cur = 0;
    for (int t = 0; t < 16; ++t) {
        if (t + 1 < 16) stage(cur ^ 1, (t + 1) * 64);
        const u16* sA = smem + cur * 12288;
        const u16* sB = sA + 4096;
#pragma unroll
        for (int ks2 = 0; ks2 < 2; ++ks2) {
            short8 af[2], bfr[4];
#pragma unroll
            for (int mt = 0; mt < 2; ++mt) {
                int Ra = 32 * wr + 16 * mt + mIdx;
                af[mt] = *(const short8*)&sA[Ra * 64 + 8 * ((ks2 * 4 + quad) ^ (Ra & 7))];
            }
#pragma unroll
            for (int nt = 0; nt < 4; ++nt) {
                int Rb = 64 * wc + 16 * nt + mIdx;
                bfr[nt] = *(const short8*)&sB[Rb * 64 + 8 * ((ks2 * 4 + quad) ^ (Rb & 7))];
            }
#pragma unroll
            for (int mt = 0; mt < 2; ++mt)
#pragma unroll
                for (int nt = 0; nt < 4; ++nt)
                    acc[mt][nt] = __builtin_amdgcn_mfma_f32_16x16x32_bf16(
                        af[mt], bfr[nt], acc[mt][nt], 0, 0, 0);
        }
        __syncthreads();
        cur ^= 1;
    }

#pragma unroll
    for (int mt = 0; mt < 2; ++mt)
#pragma unroll
        for (int r = 0; r < 4; ++r) {
            int row = m0 + 32 * wr + 16 * mt + quad * 4 + r;
#pragma unroll
            for (int nt = 0; nt < 4; ++nt) {
                int col = n0 + 64 * wc + 16 * nt + mIdx;
                C[(size_t)row * N + col] = acc[mt][nt][r] + bias[col];
            }
        }
}

// ---------------- flash attention: fragment-direct, barrier-free (R8) ---------
// 128-row 2-group structure (66us, VGPR 96, 2 blocks/CU): proven local optimum.
__global__ __launch_bounds__(256, 2) void attn_mfma(
    const u16* __restrict__ qkv, const u16* __restrict__ kp,
    const u16* __restrict__ vp, u16* __restrict__ o)
{
    __shared__ u16 sP[128 * 64];

    const int tid = threadIdx.x;
    const int wave = tid >> 6;     // 0..3
    const int lane = tid & 63;
    const int mIdx = lane & 15;
    const int quad = lane >> 4;
    const int m7 = mIdx & 7;

    // XCD-chunked swizzle (512 blocks, 8 XCDs, 64 logical blocks per XCD)
    const int bid = ((blockIdx.x & 7) << 6) | (blockIdx.x >> 3);
    const int bh = bid >> 4;          // 16 q-tiles of 128 rows per (b,h)
    const int qt = bid & 15;
    const int b = bh >> 4, h = bh & 15;
    const int q0 = qt * 128;

    // fragment bases: tile kt at +kt*4096 u16; fragment f=nb*2+c at +f*512
    const u16* kbase = kp + (size_t)bh * 32 * 4096 + lane * 8;
    const u16* vbase = vp + (size_t)bh * 32 * 4096 + lane * 8;

    // Q fragments: 2 groups of 16 rows per wave
    short8 aq[2][2];
#pragma unroll
    for (int g = 0; g < 2; ++g) {
        const u16* qrow = qkv + (size_t)b * LL * QKV_N + h * 64
                          + (size_t)(q0 + 32 * wave + 16 * g + mIdx) * QKV_N;
        aq[g][0] = *(const short8*)&qrow[quad * 8];
        aq[g][1] = *(const short8*)&qrow[32 + quad * 8];
    }

    const short8 bones = {(short)0x3F80, (short)0x3F80, (short)0x3F80, (short)0x3F80,
                          (short)0x3F80, (short)0x3F80, (short)0x3F80, (short)0x3F80};

    f32x4 Oacc[2][4];
    f32x4 lac[2];
#pragma unroll
    for (int g = 0; g < 2; ++g) {
        lac[g] = (f32x4){0.f, 0.f, 0.f, 0.f};
#pragma unroll
        for (int nb = 0; nb < 4; ++nb) Oacc[g][nb] = (f32x4){0.f, 0.f, 0.f, 0.f};
    }

    // P swizzle offsets (proven pattern)
    const int o0 = 8 * (quad ^ m7);
    const int o1 = 8 * ((quad + 4) ^ m7);
    u16* sPr0 = &sP[(32 * wave + mIdx) * 64];
    u16* sPr1 = &sP[(32 * wave + 16 + mIdx) * 64];

    short8 kfA[8], kfB[8], vf[8];

    // prologue: K fragments of tile 0
#pragma unroll
    for (int f = 0; f < 8; ++f) kfA[f] = *(const short8*)&kbase[f * 512];

    auto body = [&](short8* KC, short8* KN, int kt) {
        const size_t tb = (size_t)kt * 4096;
        // V fragments for THIS tile (consumed after S^T phase)
#pragma unroll
        for (int f = 0; f < 8; ++f) vf[f] = *(const short8*)&vbase[tb + f * 512];
        // K fragments for NEXT tile (consumed next body)
        if (kt < 31) {
#pragma unroll
            for (int f = 0; f < 8; ++f) KN[f] = *(const short8*)&kbase[tb + 4096 + f * 512];
        }
        __builtin_amdgcn_sched_barrier(0);

        // ---- S^T strips: D[key][q] = mfma(A=K-frag, B=Q-frag) ----
#pragma unroll
        for (int nb = 0; nb < 4; ++nb) {
            const int pofs = (16 * nb + 4 * quad) ^ (8 * m7);
#pragma unroll
            for (int g = 0; g < 2; ++g) {
                f32x4 st = (f32x4){0.f, 0.f, 0.f, 0.f};
                st = __builtin_amdgcn_mfma_f32_16x16x32_bf16(KC[nb * 2 + 0], aq[g][0], st, 0, 0, 0);
                st = __builtin_amdgcn_mfma_f32_16x16x32_bf16(KC[nb * 2 + 1], aq[g][1], st, 0, 0, 0);
                float p0 = exp2f(st[0]), p1 = exp2f(st[1]);
                float p2 = exp2f(st[2]), p3 = exp2f(st[3]);
                uint2 wp;
                wp.x = cvtpk_bf2(p0, p1);
                wp.y = cvtpk_bf2(p2, p3);
                *(uint2*)&((g == 0 ? sPr0 : sPr1)[pofs]) = wp;
            }
        }
        // sP rows written and read by the same wave -> no barrier.
        short8 pa00 = *(const short8*)&sPr0[o0];
        short8 pa01 = *(const short8*)&sPr0[o1];
        short8 pa10 = *(const short8*)&sPr1[o0];
        short8 pa11 = *(const short8*)&sPr1[o1];

        // l accumulation via MFMA with all-ones B (no VALU adds, no shuffles)
        lac[0] = __builtin_amdgcn_mfma_f32_16x16x32_bf16(pa00, bones, lac[0], 0, 0, 0);
        lac[0] = __builtin_amdgcn_mfma_f32_16x16x32_bf16(pa01, bones, lac[0], 0, 0, 0);
        lac[1] = __builtin_amdgcn_mfma_f32_16x16x32_bf16(pa10, bones, lac[1], 0, 0, 0);
        lac[1] = __builtin_amdgcn_mfma_f32_16x16x32_bf16(pa11, bones, lac[1], 0, 0, 0);

        // ---- O += P @ V ----
        __builtin_amdgcn_s_setprio(1);
#pragma unroll
        for (int nb = 0; nb < 4; ++nb) {
            Oacc[0][nb] = __builtin_amdgcn_mfma_f32_16x16x32_bf16(pa00, vf[nb * 2 + 0], Oacc[0][nb], 0, 0, 0);
            Oacc[0][nb] = __builtin_amdgcn_mfma_f32_16x16x32_bf16(pa01, vf[nb * 2 + 1], Oacc[0][nb], 0, 0, 0);
            Oacc[1][nb] = __builtin_amdgcn_mfma_f32_16x16x32_bf16(pa10, vf[nb * 2 + 0], Oacc[1][nb], 0, 0, 0);
            Oacc[1][nb] = __builtin_amdgcn_mfma_f32_16x16x32_bf16(pa11, vf[nb * 2 + 1], Oacc[1][nb], 0, 0, 0);
        }
        __builtin_amdgcn_s_setprio(0);
    };

    for (int kt2 = 0; kt2 < 16; ++kt2) {
        body(kfA, kfB, 2 * kt2);
        body(kfB, kfA, 2 * kt2 + 1);
    }

    // epilogue: l for q-row quad*4+r (within group g) sits in lac[g][r] of
    // EVERY lane (all-ones B makes all columns equal) — no shuffles needed.
#pragma unroll
    for (int g = 0; g < 2; ++g)
#pragma unroll
        for (int r = 0; r < 4; ++r) {
            float linv = 1.f / lac[g][r];
            const int rowg = b * LL + q0 + 32 * wave + 16 * g + quad * 4 + r;
#pragma unroll
            for (int nb = 0; nb < 4; ++nb) {
                o[(size_t)rowg * DIMM + h * 64 + 16 * nb + mIdx] =
                    f2bf(Oacc[g][nb][r] * linv);
            }
        }
}

extern "C" void kernel_launch(void* const* d_in, const int* in_sizes, int n_in,
                              void* d_out, int out_size, void* d_ws, size_t ws_size,
                              hipStream_t stream) {
    const float* x       = (const float*)d_in[0];
    const float* pe      = (const float*)d_in[1];
    const float* w_qkv   = (const float*)d_in[2];
    const float* q_scale = (const float*)d_in[3];
    const float* k_scale = (const float*)d_in[4];
    const float* w_proj  = (const float*)d_in[5];
    const float* b_proj  = (const float*)d_in[6];
    float* out = (float*)d_out;

    char* ws = (char*)d_ws;
    u16* qkv    = (u16*)ws;  ws += (size_t)4096 * 3072 * 2;
    u16* o      = (u16*)ws;  ws += (size_t)4096 * 1024 * 2;
    u16* xb     = (u16*)ws;  ws += (size_t)4096 * 1024 * 2;   // A-fragment-packed
    u16* wqkvt  = (u16*)ws;  ws += (size_t)3072 * 1024 * 2;   // B-fragment-packed
    u16* wprojt = (u16*)ws;  ws += (size_t)1024 * 1024 * 2;   // row-major [N][K]
    u16* kpack  = (u16*)ws;  ws += (size_t)32 * 32 * 4096 * 2;   // 8.4 MB
    u16* vpack  = (u16*)ws;  ws += (size_t)32 * 32 * 4096 * 2;   // 8.4 MB

    // 0. all conversions in ONE dispatch
    conv_all<<<3072, 256, 0, stream>>>(x, xb, w_qkv, wqkvt, w_proj, wprojt);

    // 1. QKV projection: 1536 blocks of 128x64 tiles (R16: 2x TLP)
    gemm_qkv_all<<<1536, 256, 0, stream>>>(
        xb, wqkvt, qkv, kpack, vpack, pe, q_scale, k_scale);

    // 2. attention (R8: 128-row tiles, K ping-pong, VGPR 96)
    attn_mfma<<<BB * HH * (LL / 128), 256, 0, stream>>>(qkv, kpack, vpack, o);

    // 3. output projection + bias (f32 out)
    gemm_proj<<<512, 256, 0, stream>>>(o, wprojt, b_proj, out);
}